// Round 13
// baseline (631.859 us; speedup 1.0000x reference)
//
#include <hip/hip_runtime.h>
#include <hip/hip_fp16.h>
#include <math.h>

// Problem constants: B=8, Tt=16, C=1, H=W=512, 4 in-channels, 10 T-planes.
#define Bd 8
#define Td 16
#define Hd 512
#define Wd 512
#define HWc (Hd * Wd)          // 262144
#define NPIX (Bd * HWc)        // 2,097,152

// ---------------- conv tiling: 128x16 tile, 4 px/thread (2x2), 512 threads ---
#define VTW 128
#define VTH 16
#define VRW 130
#define VRH 18
#define VP  132
#define VTHR 512

// ---------------- fused-step tiling: 128x64 core, halo 6, 2-col pairs --------
#define WCR 128                // core rows
#define WCC 64                 // core cols
#define WH  6                  // halo
#define WTR 140                // region rows
#define WTC 76                 // region cols
#define WP2 78                 // LDS row pitch (EVEN, for b64 alignment)
#define WTHR 1024
#define NPAIR 38               // column pairs (76/2)
#define NGRP 23                // row groups; 23*6 = 138 interior rows exactly
#define RPT 6                  // owned rows per thread

// ---------------------------------------------------------------------------
// Kernel 1: tiled conv  T = conv2d(x[:, -4:, 0], W_unet, SAME) + b_unet,
// fused with xt0 = stencil(x[:,15,0], T_fp32) -> out[:, 0].
// 4 px/thread (2x2). launch_bounds(512,2): VGPR cap 256 -> no spill (round-12
// (512,4) squeezed to 64 VGPR and spilled: +40 MB scratch traffic).
// T stored as half2 pairs: plane q holds (T[2q], T[2q+1]); layout (B,5,H,W).
// ---------------------------------------------------------------------------
__global__ __launch_bounds__(VTHR, 2)
void conv_step0_kernel(const float* __restrict__ x,
                       const float* __restrict__ Wu,
                       const float* __restrict__ bu,
                       __half2* __restrict__ T,
                       float* __restrict__ out) {
    __shared__ __align__(16) float sX[4][VRH][VP];   // 38 KB

    int bx  = blockIdx.x;           // 1024 = 8 b * 32 row-bands * 4 col-bands
    int b   = bx >> 7;
    int rem = bx & 127;
    int by  = rem >> 2;
    int bc  = rem & 3;
    int i0  = by * VTH;
    int j0  = bc * VTW;

    const float* xb = x + ((size_t)b * Td + 12) * HWc;
    int tid = threadIdx.x;

    for (int idx = tid; idx < 4 * VRH * VRW; idx += VTHR) {
        int ch = idx / (VRH * VRW);
        int r2 = idx - ch * (VRH * VRW);
        int r  = r2 / VRW;
        int c  = r2 - r * VRW;
        int gi = i0 + r - 1, gj = j0 + c - 1;
        float v = 0.0f;
        if ((unsigned)gi < (unsigned)Hd && (unsigned)gj < (unsigned)Wd)
            v = xb[(size_t)ch * HWc + gi * Wd + gj];
        sX[ch][r][c] = v;
    }
    __syncthreads();

    int tx = tid & 63;              // col pair: cols 2tx, 2tx+1
    int ty = tid >> 6;              // row pair: rows 2ty, 2ty+1

    float t00[10], t01[10], t10[10], t11[10];
    #pragma unroll
    for (int o = 0; o < 10; ++o) {
        float bv = bu[o];
        t00[o] = bv; t01[o] = bv; t10[o] = bv; t11[o] = bv;
    }

    float w[4][4];
    #pragma unroll
    for (int ch = 0; ch < 4; ++ch) {
        #pragma unroll
        for (int rr = 0; rr < 4; ++rr) {
            const float* rp = &sX[ch][2 * ty + rr][2 * tx];
            float2 a  = *(const float2*)rp;
            float2 b2 = *(const float2*)(rp + 2);
            w[rr][0] = a.x; w[rr][1] = a.y; w[rr][2] = b2.x; w[rr][3] = b2.y;
        }
        #pragma unroll
        for (int kh = 0; kh < 3; ++kh) {
            #pragma unroll
            for (int o = 0; o < 10; ++o) {
                float wt0 = Wu[((o * 4 + ch) * 3 + kh) * 3 + 0];
                float wt1 = Wu[((o * 4 + ch) * 3 + kh) * 3 + 1];
                float wt2 = Wu[((o * 4 + ch) * 3 + kh) * 3 + 2];
                t00[o] += w[kh][0] * wt0 + w[kh][1] * wt1 + w[kh][2] * wt2;
                t01[o] += w[kh][1] * wt0 + w[kh][2] * wt1 + w[kh][3] * wt2;
                t10[o] += w[kh + 1][0] * wt0 + w[kh + 1][1] * wt1 + w[kh + 1][2] * wt2;
                t11[o] += w[kh + 1][1] * wt0 + w[kh + 1][2] * wt1 + w[kh + 1][3] * wt2;
            }
        }
    }
    // w[][] now holds channel 3 (= x slice 15).

    int gi0 = i0 + 2 * ty;
    int gj0 = j0 + 2 * tx;
    size_t pix0 = (size_t)gi0 * Wd + gj0;
    size_t pix1 = pix0 + Wd;
    __half2* Tb = T + (size_t)b * 5 * HWc;
    #pragma unroll
    for (int q = 0; q < 5; ++q) {
        __half2 a0 = __floats2half2_rn(t00[2 * q], t00[2 * q + 1]);
        __half2 a1 = __floats2half2_rn(t01[2 * q], t01[2 * q + 1]);
        __half2 b0 = __floats2half2_rn(t10[2 * q], t10[2 * q + 1]);
        __half2 b1 = __floats2half2_rn(t11[2 * q], t11[2 * q + 1]);
        uint2 p0, p1;
        p0.x = *(unsigned*)&a0; p0.y = *(unsigned*)&a1;
        p1.x = *(unsigned*)&b0; p1.y = *(unsigned*)&b1;
        *(uint2*)(Tb + (size_t)q * HWc + pix0) = p0;
        *(uint2*)(Tb + (size_t)q * HWc + pix1) = p1;
    }

    // step0 on channel 3: k = dj*3+di multiplies x15[i+di-1, j+dj-1].
    float o00 = t00[9], o01 = t01[9], o10 = t10[9], o11 = t11[9];
    #pragma unroll
    for (int dj = 0; dj < 3; ++dj)
        #pragma unroll
        for (int di = 0; di < 3; ++di) {
            int k = dj * 3 + di;
            o00 += w[di][dj]         * t00[k];
            o01 += w[di][dj + 1]     * t01[k];
            o10 += w[di + 1][dj]     * t10[k];
            o11 += w[di + 1][dj + 1] * t11[k];
        }
    float* ob = out + (size_t)b * Td * HWc;
    float2 v0; v0.x = o00; v0.y = o01;
    float2 v1; v1.x = o10; v1.y = o11;
    *(float2*)(ob + pix0) = v0;
    *(float2*)(ob + pix1) = v1;
}

// ---------------------------------------------------------------------------
// Kernel 2: one scan-body iteration = 6 fused stencil steps on a 128x64 core
// (region 140x76, pitch 78). Thread owns a 2-col x 6-row strip: per row one
// scalar + one float2 + one scalar LDS read covers both columns' 3x3 windows
// (2.5 LDS instr/px vs 4 before). T loaded as uint2 (both cols, 8B aligned).
// Edge pairs (u=0/37) compute both cols, write only the interior one; the
// garbage window col feeds only a write-masked output. Sigmoid at even
// sub-steps. Region ring never written; contamination <=1 px/step; halo 6
// protects the core. 256 blocks = 1/CU, one round. VGPR ~95 < 128 cap.
// ---------------------------------------------------------------------------
__global__ __launch_bounds__(WTHR, 4)
void fused6_pair_kernel(const float* __restrict__ xin,   // out slot t-1 base
                        const __half2* __restrict__ T,
                        float* __restrict__ xout) {      // out slot t base
    __shared__ __align__(16) float sA[WTR * WP2];
    __shared__ __align__(16) float sB[WTR * WP2];

    int tile = blockIdx.x;          // 256 = 8 b * 4 tr * 8 tc
    int b  = tile >> 5;
    int tr = (tile >> 3) & 3;
    int tc = tile & 7;
    int ri = tr * WCR - WH;
    int rj = tc * WCC - WH;         // even

    const float* xb = xin + (size_t)b * Td * HWc;
    const __half2* Tb = T + (size_t)b * 5 * HWc;
    int tid = threadIdx.x;

    // Stage sA (zeros outside image).
    for (int idx = tid; idx < WTR * WTC; idx += WTHR) {
        int r = idx / WTC, c = idx - r * WTC;
        int gi = ri + r, gj = rj + c;
        float v = 0.0f;
        if ((unsigned)gi < (unsigned)Hd && (unsigned)gj < (unsigned)Wd)
            v = xb[gi * Wd + gj];
        sA[r * WP2 + c] = v;
    }
    // Zero sB's ring once (never written by the step loop; interior fully
    // rewritten each step before being read).
    for (int idx = tid; idx < 2 * WTC; idx += WTHR) {
        int r = (idx < WTC) ? 0 : (WTR - 1);
        int c = (idx < WTC) ? idx : idx - WTC;
        sB[r * WP2 + c] = 0.0f;
    }
    for (int idx = tid; idx < 2 * WTR; idx += WTHR) {
        int r = (idx < WTR) ? idx : idx - WTR;
        int c = (idx < WTR) ? 0 : (WTC - 1);
        sB[r * WP2 + c] = 0.0f;
    }

    int g = tid / NPAIR;            // row group (0..22 active)
    int u = tid - g * NPAIR;        // column pair 0..37
    bool active = (g < NGRP);
    int rs  = 1 + g * RPT;          // first owned row (1..133)
    int c0  = 2 * u;                // first owned col (even)
    int gj0 = rj + c0;
    bool pairin = (unsigned)gj0 < (unsigned)Wd;   // both cols in-image
    bool w0 = active && (u >= 1);                 // col c0 interior
    bool w1 = active && (u <= NPAIR - 2);         // col c0+1 interior
    // Clamped side-read offsets; clamped values feed only masked outputs.
    int offL = (u == 0) ? 1 : (c0 - 1);           // col c0-1
    int offR = (u == NPAIR - 1) ? (c0 - 2) : (c0 + 2);  // col c0+2

    // T coefficients: uint2 = both columns' half2, per plane per row.
    __half2 tA[RPT][5], tB[RPT][5];
    #pragma unroll
    for (int jj = 0; jj < RPT; ++jj) {
        int r  = rs + jj;
        int gi = ri + r;
        bool ok = active && ((unsigned)gi < (unsigned)Hd) && pairin;
        #pragma unroll
        for (int q = 0; q < 5; ++q) {
            uint2 pk; pk.x = 0u; pk.y = 0u;
            if (ok) pk = *(const uint2*)(Tb + (size_t)q * HWc + gi * Wd + gj0);
            tA[jj][q] = *(__half2*)&pk.x;
            tB[jj][q] = *(__half2*)&pk.y;
        }
    }
    __syncthreads();

    float* cur = sA;
    float* nxt = sB;

    #pragma unroll
    for (int s = 1; s <= 6; ++s) {
        if (active) {
            // Window rows r-1, r, r+1; streamed. Per row: ly = col c0-1,
            // m = cols (c0, c0+1), rx = col c0+2.
            int base = (rs - 1) * WP2;
            float  ly0 = cur[base + offL];
            float2 m0  = *(const float2*)&cur[base + c0];
            float  rx0 = cur[base + offR];
            base += WP2;
            float  ly1 = cur[base + offL];
            float2 m1  = *(const float2*)&cur[base + c0];
            float  rx1 = cur[base + offR];
            #pragma unroll
            for (int jj = 0; jj < RPT; ++jj) {
                int r  = rs + jj;
                int b2 = (r + 1) * WP2;
                float  ly2 = cur[b2 + offL];
                float2 m2  = *(const float2*)&cur[b2 + c0];
                float  rx2 = cur[b2 + offR];

                float2 qA0 = __half22float2(tA[jj][0]);  // T0,T1 col0
                float2 qA1 = __half22float2(tA[jj][1]);  // T2,T3
                float2 qA2 = __half22float2(tA[jj][2]);  // T4,T5
                float2 qA3 = __half22float2(tA[jj][3]);  // T6,T7
                float2 qA4 = __half22float2(tA[jj][4]);  // T8,T9
                float2 qB0 = __half22float2(tB[jj][0]);
                float2 qB1 = __half22float2(tB[jj][1]);
                float2 qB2 = __half22float2(tB[jj][2]);
                float2 qB3 = __half22float2(tB[jj][3]);
                float2 qB4 = __half22float2(tB[jj][4]);

                // k = dj*3+di multiplies x[r+di-1][c+dj-1]
                float a0 = qA4.y
                         + ly0  * qA0.x + ly1  * qA0.y + ly2  * qA1.x
                         + m0.x * qA1.y + m1.x * qA2.x + m2.x * qA2.y
                         + m0.y * qA3.x + m1.y * qA3.y + m2.y * qA4.x;
                float a1 = qB4.y
                         + m0.x * qB0.x + m1.x * qB0.y + m2.x * qB1.x
                         + m0.y * qB1.y + m1.y * qB2.x + m2.y * qB2.y
                         + rx0  * qB3.x + rx1  * qB3.y + rx2  * qB4.x;
                if ((s & 1) == 0) {
                    a0 = 1.0f / (1.0f + __expf(-a0));
                    a1 = 1.0f / (1.0f + __expf(-a1));
                }

                int gi = ri + r;
                bool inimg = ((unsigned)gi < (unsigned)Hd) && pairin;
                float v0 = inimg ? a0 : 0.0f;
                float v1 = inimg ? a1 : 0.0f;

                if (w0 && w1) {
                    float2 wv; wv.x = v0; wv.y = v1;
                    *(float2*)&nxt[r * WP2 + c0] = wv;
                } else {
                    if (w1) nxt[r * WP2 + c0 + 1] = v1;   // u == 0
                    if (w0) nxt[r * WP2 + c0]     = v0;   // u == 37
                }

                ly0 = ly1; m0 = m1; rx0 = rx1;
                ly1 = ly2; m1 = m2; rx1 = rx2;
            }
        }
        __syncthreads();
        float* tmp = cur; cur = nxt; nxt = tmp;
    }

    // After 6 swaps the result is back in sA (== cur). Write 128x64 core.
    float* ob = xout + (size_t)b * Td * HWc;
    for (int idx = tid; idx < WCR * WCC; idx += WTHR) {
        int rr = idx >> 6, cc = idx & 63;
        ob[(ri + WH + rr) * Wd + (rj + WH + cc)] = cur[(WH + rr) * WP2 + (WH + cc)];
    }
}

// ---------------------------------------------------------------------------
// Workspace: T only (B*5*H*W half2 = 40 MB).
// ---------------------------------------------------------------------------
extern "C" void kernel_launch(void* const* d_in, const int* in_sizes, int n_in,
                              void* d_out, int out_size, void* d_ws, size_t ws_size,
                              hipStream_t stream) {
    const float* x  = (const float*)d_in[0];
    const float* Wu = (const float*)d_in[1];
    const float* bu = (const float*)d_in[2];
    float* out = (float*)d_out;
    __half2* T = (__half2*)d_ws;

    conv_step0_kernel<<<1024, VTHR, 0, stream>>>(x, Wu, bu, T, out);

    for (int t = 1; t < Td; ++t)
        fused6_pair_kernel<<<256, WTHR, 0, stream>>>(out + (size_t)(t - 1) * HWc, T,
                                                     out + (size_t)t * HWc);
}